// Round 6
// baseline (436.986 us; speedup 1.0000x reference)
//
#include <hip/hip_runtime.h>

// GODE on MI355X. bf16/fp8 MFMA, fp32 accum, h TRANSPOSED: hT[(b*128+d)][n].
// R5 algebra: (adj@h)@W_half == adj@(h@W_half)  -> big GEMM per step is
// [64 j x 2048 n2, K=2048] per batch, operands hW8[(b*64+j)][n], adj8[n2][n]
// (fp8 e4m3; adj pre-scaled x2^16, C rescaled before tanh — R10, verified).
// R11: fs2 is latency-bound in barrier-locked staging (R10: fp8 halved bytes,
// time unchanged; 2 blocks/CU drain vmcnt(0) in phase). Fix: only A (shared
// by all 4 waves) goes to LDS — staged in 4 chunks of K=512 (8 barriers TOTAL
// per kernel). B rows are wave-private -> per-lane direct global->VGPR 8B
// loads (R8-proven pattern; its failure was A-redundancy, not B), streaming
// L2 with no barrier coupling -> compiler pipelines freely, blocks overlap.
// mlp: R0 structure + quad-major LDS panels only (conflict fix, R6 layout).

typedef unsigned short u16;
typedef unsigned char  u8;
typedef unsigned int   u32;
typedef unsigned long long u64;
typedef __attribute__((ext_vector_type(8))) short bf8;  // 8 raw bf16 (4 VGPRs)
typedef __attribute__((ext_vector_type(4))) float f4;

#define AS1 __attribute__((address_space(1)))
#define AS3 __attribute__((address_space(3)))

__device__ __forceinline__ void gl_lds16(const void* g, void* l) {
  __builtin_amdgcn_global_load_lds((const AS1 u32*)g, (AS3 u32*)l, 16, 0, 0);
}
__device__ __forceinline__ float bf2f(u16 v) {
  u32 u = ((u32)v) << 16; return __builtin_bit_cast(float, u);
}
__device__ __forceinline__ u16 f2bf(float f) {  // RNE
  u32 u = __builtin_bit_cast(u32, f);
  return (u16)((u + 0x7fffu + ((u >> 16) & 1u)) >> 16);
}
// software float -> OCP e4m3 (RNE, saturate to 448, no inf)
__device__ __forceinline__ u8 f2fp8(float f) {
  u32 u = __builtin_bit_cast(u32, f);
  u32 s = (u >> 24) & 0x80u;
  int e = (int)((u >> 23) & 0xFFu) - 127;
  u32 m = u & 0x7FFFFFu;
  if (e > 8 || (e == 8 && m >= 0x700000u)) return (u8)(s | 0x7Eu);  // clamp 448
  if (e >= -6) {
    u32 keep = m >> 20, rest = m & 0xFFFFFu;
    keep += (rest > 0x80000u || (rest == 0x80000u && (keep & 1u))) ? 1u : 0u;
    u32 v = ((u32)(e + 7) << 3) + keep;       // mantissa carry rolls into exp
    if (v >= 0x7Fu) v = 0x7Eu;
    return (u8)(s | v);
  }
  if (e < -10) return (u8)s;                   // below half of min subnormal
  u32 mm = 0x800000u | m;
  int sh = 14 - e;                             // 21..24
  u32 q = mm >> sh, rem = mm & ((1u << sh) - 1u), half = 1u << (sh - 1);
  q += (rem > half || (rem == half && (q & 1u))) ? 1u : 0u;
  return (u8)(s | q);
}
__device__ __forceinline__ float ldf(const void* p, size_t i, u32 isf32) {
  return isf32 ? ((const float*)p)[i] : bf2f(((const u16*)p)[i]);
}

// ---- quad-major bf16 staging: [R/16 groups][4 kq][16 rows][8 bf16], 1KB/grp.
// gl_lds lane l -> (row=l&15, kq=l>>4) = linear l*16B. Frag read lane(col,quad):
// g*512 + quad*128 + col*8 (u16) -> 16 consecutive 16B units: conflict-free.
__device__ __forceinline__ void stage128x32q(const u16* g, int stride, u16* lds,
                                             int wave, int lane) {
  int r = lane & 15, qk = (lane >> 4) * 8;
  gl_lds16(g + (size_t)(wave * 16 + r) * stride + qk, lds + wave * 512);
  gl_lds16(g + (size_t)((wave + 4) * 16 + r) * stride + qk, lds + (wave + 4) * 512);
}

// ---------------- dtype detection ----------------
__global__ void detect_dtype(const u16* __restrict__ x_raw, u32* __restrict__ flag) {
  __shared__ int s;
  int tid = threadIdx.x;
  if (tid == 0) s = 0;
  __syncthreads();
  int huge = 0;
#pragma unroll
  for (int j = 0; j < 16; ++j) {
    u16 v = x_raw[tid * 16 + j];
    u32 e = (v >> 7) & 0xFF;
    if (e >= 0xC0) huge = 1;          // |v| >= 2^64: impossible for N(0,1) bf16
  }
  if (huge) atomicOr(&s, 1);
  __syncthreads();
  if (tid == 0) flag[0] = (u32)s;     // 1 = f32 inputs, 0 = bf16 inputs
}

// ---------------- adj -> fp8 (x 2^16) ----------------
__global__ void cvt_fp8(const void* __restrict__ in, u8* __restrict__ out,
                        int n, const u32* __restrict__ flag) {
  u32 isf32 = flag[0];
  int gid = blockIdx.x * 256 + threadIdx.x;
  if (gid * 4 >= n) return;
  size_t i = (size_t)gid * 4;
  u32 pk = 0;
#pragma unroll
  for (int j = 0; j < 4; ++j)
    pk |= (u32)f2fp8(ldf(in, i + j, isf32) * 65536.0f) << (8 * j);
  *(u32*)&out[i] = pk;
}

// ---------------- weight pre-transpose ----------------
// WaT[256][256]=Wa^T, WbT[128][256]=Wb^T, W1T[64][128]=W1[:, :64]^T, W2T[64][128]=W2[:, 64:]^T
__global__ void prep_weights(const void* __restrict__ Wa, const void* __restrict__ Wb,
                             const void* __restrict__ W1, const void* __restrict__ W2,
                             u16* __restrict__ WaT, u16* __restrict__ WbT,
                             u16* __restrict__ W1T, u16* __restrict__ W2T,
                             const u32* __restrict__ flag) {
  u32 isf32 = flag[0];
  int i = blockIdx.x * 256 + threadIdx.x;
  if (i < 65536) {
    int o = i >> 8, k = i & 255; WaT[o * 256 + k] = f2bf(ldf(Wa, (size_t)k * 256 + o, isf32));
  } else if (i < 98304) {
    int j = i - 65536; int o = j >> 8, k = j & 255;
    WbT[o * 256 + k] = f2bf(ldf(Wb, (size_t)k * 128 + o, isf32));
  } else if (i < 106496) {
    int j = i - 98304; int jj = j >> 7, k = j & 127;
    W1T[jj * 128 + k] = f2bf(ldf(W1, (size_t)k * 128 + jj, isf32));
  } else {
    int j = i - 106496; int jj = j >> 7, k = j & 127;
    W2T[jj * 128 + k] = f2bf(ldf(W2, (size_t)k * 128 + 64 + jj, isf32));
  }
}

// ---------------- fused MLP + first hW (R0 rhythm + quad-major panels) ------
// hT = tanh(relu([x,hz]@Wa+ba)@Wb+bb)  (transposed store), and
// hW1[(b*64+j)][n] = fp8( sum_d W1T[j][d] * h0[n-row][d] ).
__global__ __launch_bounds__(256, 2) void mlp_fused(const void* __restrict__ x,
                                                    const void* __restrict__ hz,
                                                    const u16* __restrict__ WaT,
                                                    const void* __restrict__ ba,
                                                    const u16* __restrict__ WbT,
                                                    const void* __restrict__ bb,
                                                    const u16* __restrict__ W1T,
                                                    u16* __restrict__ hT,
                                                    u8* __restrict__ hW,
                                                    const u32* __restrict__ flag) {
  __shared__ __align__(16) u16 Z[64 * 264];     // 33.8 KB
  __shared__ __align__(16) u16 pool[10240];     // 20 KB: lA 64x32q | lB 256x32q; later hN
  u16* lA = pool;
  u16* lB = pool + 2048;
  u16* hN = pool;                               // 64*136 = 8704 u16, overlays post-use
  u32 isf32 = flag[0];
  int tid = threadIdx.x, lane = tid & 63, wave = tid >> 6;
  int col = lane & 15, quad = lane >> 4;
  int r0 = blockIdx.x * 64;
  int b = r0 >> 11;

  // phase 1: Z = relu(u @ Wa + ba), u = [x|hz], tile 64 x 256
  f4 acc[4][4] = {};
  for (int kk = 0; kk < 8; ++kk) {
    int k0 = kk * 32;
    const void* src = (kk < 4) ? x : hz;
    int csrc = (kk < 4) ? k0 : (k0 - 128);
    __syncthreads();
    {  // stage A 64x32 (quad-major dest) with dtype convert
      int row = tid >> 2, c0 = (tid & 3) * 8;
      size_t g = (size_t)(r0 + row) * 128 + csrc + c0;
      uint4 pk;
      if (isf32) {
        f4 v0 = *(const f4*)&((const float*)src)[g];
        f4 v1 = *(const f4*)&((const float*)src)[g + 4];
        pk.x = (u32)f2bf(v0[0]) | ((u32)f2bf(v0[1]) << 16);
        pk.y = (u32)f2bf(v0[2]) | ((u32)f2bf(v0[3]) << 16);
        pk.z = (u32)f2bf(v1[0]) | ((u32)f2bf(v1[1]) << 16);
        pk.w = (u32)f2bf(v1[2]) | ((u32)f2bf(v1[3]) << 16);
      } else {
        pk = *(const uint4*)&((const u16*)src)[g];
      }
      *(uint4*)&lA[(row >> 4) * 512 + (tid & 3) * 128 + (row & 15) * 8] = pk;
    }
    stage128x32q(WaT + k0, 256, lB, wave, lane);
    stage128x32q(WaT + (size_t)128 * 256 + k0, 256, lB + 4096, wave, lane);
    __syncthreads();
    bf8 af[4], bfr[4];
#pragma unroll
    for (int mi = 0; mi < 4; ++mi) af[mi] = *(const bf8*)&lA[mi * 512 + quad * 128 + col * 8];
#pragma unroll
    for (int nj = 0; nj < 4; ++nj) bfr[nj] = *(const bf8*)&lB[(wave * 4 + nj) * 512 + quad * 128 + col * 8];
#pragma unroll
    for (int mi = 0; mi < 4; ++mi)
#pragma unroll
      for (int nj = 0; nj < 4; ++nj)
        acc[mi][nj] = __builtin_amdgcn_mfma_f32_16x16x32_bf16(af[mi], bfr[nj], acc[mi][nj], 0, 0, 0);
  }
#pragma unroll
  for (int mi = 0; mi < 4; ++mi)
#pragma unroll
    for (int nj = 0; nj < 4; ++nj) {
      int o = wave * 64 + nj * 16 + col;
      float bav = ldf(ba, o, isf32);
      int rl = mi * 16 + quad * 4;
#pragma unroll
      for (int r = 0; r < 4; ++r)
        Z[(rl + r) * 264 + o] = f2bf(fmaxf(acc[mi][nj][r] + bav, 0.f));
    }
  __syncthreads();

  // phase 2: h0 = tanh(Z @ Wb + bb); A-frags from Z (stride 264, 2-way free)
  f4 acc2[4][2] = {};
  for (int kk = 0; kk < 8; ++kk) {
    int k0 = kk * 32;
    if (kk) __syncthreads();
    stage128x32q(WbT + k0, 256, lB, wave, lane);
    __syncthreads();
    bf8 az[4], bw[2];
#pragma unroll
    for (int mi = 0; mi < 4; ++mi) az[mi] = *(const bf8*)&Z[(mi * 16 + col) * 264 + k0 + quad * 8];
#pragma unroll
    for (int nj = 0; nj < 2; ++nj) bw[nj] = *(const bf8*)&lB[(wave * 2 + nj) * 512 + quad * 128 + col * 8];
#pragma unroll
    for (int mi = 0; mi < 4; ++mi)
#pragma unroll
      for (int nj = 0; nj < 2; ++nj)
        acc2[mi][nj] = __builtin_amdgcn_mfma_f32_16x16x32_bf16(az[mi], bw[nj], acc2[mi][nj], 0, 0, 0);
  }
  __syncthreads();   // all waves done with lB before hN overlay

  // epilogue: tanh(+bb) -> global hT (transposed) AND hN[r][d] staging for hW1
#pragma unroll
  for (int mi = 0; mi < 4; ++mi)
#pragma unroll
    for (int nj = 0; nj < 2; ++nj) {
      int d = wave * 32 + nj * 16 + col;
      float bbv = ldf(bb, d, isf32);
      int rl = mi * 16 + quad * 4;
      int rabs = r0 + rl;
      int n = rabs & 2047;
      u16 p[4];
#pragma unroll
      for (int r = 0; r < 4; ++r) {
        p[r] = f2bf(tanhf(acc2[mi][nj][r] + bbv));
        hN[(rl + r) * 136 + d] = p[r];
      }
      u64 pk = (u64)p[0] | ((u64)p[1] << 16) | ((u64)p[2] << 32) | ((u64)p[3] << 48);
      *(u64*)&hT[(size_t)(b * 128 + d) * 2048 + n] = pk;
    }
  __syncthreads();

  // hW1: out[j][r] = sum_d W1T[j][d] * hN[r][d]; wave covers r in [wave*16, wave*16+16)
  f4 acc3[4] = {};
#pragma unroll
  for (int ks = 0; ks < 4; ++ks) {
    bf8 aw[4], bg;
#pragma unroll
    for (int mi = 0; mi < 4; ++mi)
      aw[mi] = *(const bf8*)&W1T[(size_t)(mi * 16 + col) * 128 + ks * 32 + quad * 8];
    bg = *(const bf8*)&hN[(wave * 16 + col) * 136 + ks * 32 + quad * 8];
#pragma unroll
    for (int mi = 0; mi < 4; ++mi)
      acc3[mi] = __builtin_amdgcn_mfma_f32_16x16x32_bf16(aw[mi], bg, acc3[mi], 0, 0, 0);
  }
#pragma unroll
  for (int mi = 0; mi < 4; ++mi) {
    int rloc = wave * 16 + col;
    int ng = (r0 & 2047) + rloc;
#pragma unroll
    for (int r = 0; r < 4; ++r) {
      int j = mi * 16 + quad * 4 + r;
      hW[(size_t)(b * 64 + j) * 2048 + ng] = f2fp8(acc3[mi][r]);
    }
  }
}

// ---------------- fused diffusion step (v8: A-only LDS, B direct-stream) ----
// Big GEMM (fp8): G[m=(b,j)][n2] = sum_n hW8[(b*64+j)][n] * adj8[n2][n],
// C = acc * 2^-16. Tile 64x128, 4 waves. A (64 rows, shared by all waves)
// staged to LDS in 4 chunks of K=512 (32KB) -> 8 barriers TOTAL. B rows are
// wave-private: per-lane 8B direct global->VGPR loads inside the barrier-free
// ks-loop (streaming, 1x redundancy, compiler-pipelined).
// LDS A layout: 1KB subtile = 32 rows x 32 k, cells [kh2][row32][16B];
// chunk = [2 rowgrp][16 kc] subtiles. Epilogue identical to R10.
__global__ __launch_bounds__(256, 2) void fused_step2(const u16* __restrict__ hin,
                                                      const u8* __restrict__ hW8,
                                                      const u8* __restrict__ adj8,
                                                      const u16* __restrict__ WnT,
                                                      const void* __restrict__ eps,
                                                      u16* __restrict__ hout,
                                                      u8* __restrict__ hWout,
                                                      int half, const u32* __restrict__ flag) {
  __shared__ __align__(16) u16 smem[17408];   // 34.8 KB: A-chunk 32KB; gN overlays
  u8* lA8 = (u8*)smem;
  u16* gN = smem;               // [128][136] = 17408 u16, overlays post K-loop
  u32 isf32 = flag[0];
  int tid = threadIdx.x, lane = tid & 63, wave = tid >> 6;
  int col = lane & 15, quad = lane >> 4;
  int b = blockIdx.y;
  int n0 = blockIdx.x * 128;

  const u8* Arow = hW8 + (size_t)(b * 64) * 2048;
  const u8* Bb = adj8 + (size_t)(n0 + wave * 32 + col) * 2048 + quad * 8;
  int r32 = lane & 31, kh16 = (lane >> 5) * 16;
  int baseQ = (quad >> 1) * 512 + (quad & 1) * 8 + col * 16;

  f4 acc[4][2] = {};
#pragma unroll 1
  for (int ch = 0; ch < 4; ++ch) {
    {  // stage A chunk ch: 64 rows x 512 k = 32 subtiles; 8 gl_lds per wave
      int g = wave >> 1, kc0 = (wave & 1) * 8;
      const u8* As = Arow + (size_t)(g * 32 + r32) * 2048 + ch * 512 + kh16;
      u8* Ad = lA8 + g * 16384 + kc0 * 1024;
#pragma unroll
      for (int q = 0; q < 8; ++q)
        gl_lds16(As + (kc0 + q) * 32, Ad + q * 1024);
    }
    __syncthreads();
#pragma unroll
    for (int ks = 0; ks < 16; ++ks) {
      long long bfr[2];
#pragma unroll
      for (int nj = 0; nj < 2; ++nj)
        bfr[nj] = *(const long long*)&Bb[(size_t)nj * 16 * 2048 + ch * 512 + ks * 32];
      long long af[4];
#pragma unroll
      for (int mi = 0; mi < 4; ++mi)
        af[mi] = *(const long long*)&lA8[((mi >> 1) * 16 + ks) * 1024 + (mi & 1) * 256 + baseQ];
#pragma unroll
      for (int mi = 0; mi < 4; ++mi)
#pragma unroll
        for (int nj = 0; nj < 2; ++nj)
          acc[mi][nj] = __builtin_amdgcn_mfma_f32_16x16x32_fp8_fp8(af[mi], bfr[nj], acc[mi][nj], 0, 0, 0);
    }
    __syncthreads();
  }

  bool has_eps = (eps != nullptr);
  bool mk_hw = (WnT != nullptr);
  int dBase = half * 64;
  const float INV = 1.52587890625e-05f;   // 2^-16 (adj pre-scale)
  // update + write updated half; stage nh into gN[n][dBase+j]
#pragma unroll
  for (int mi = 0; mi < 4; ++mi)
#pragma unroll
    for (int nj = 0; nj < 2; ++nj) {
      int j0 = mi * 16 + quad * 4;
      int nl = wave * 32 + nj * 16 + col;
      int n = n0 + nl;
      float ev[4];
      if (has_eps) {
        size_t eoff = ((size_t)b * 2048 + n) * 64 + j0;
        if (isf32) {
          f4 e = *(const f4*)&((const float*)eps)[eoff];
          ev[0] = e[0]; ev[1] = e[1]; ev[2] = e[2]; ev[3] = e[3];
        } else {
          u64 e = *(const u64*)&((const u16*)eps)[eoff];
          ev[0] = bf2f((u16)e); ev[1] = bf2f((u16)(e >> 16));
          ev[2] = bf2f((u16)(e >> 32)); ev[3] = bf2f((u16)(e >> 48));
        }
      }
      u16 pv[4];
#pragma unroll
      for (int r = 0; r < 4; ++r) {
        int j = j0 + r;
        size_t idx = (size_t)(b * 128 + dBase + j) * 2048 + n;
        float hold = bf2f(hin[idx]);
        float nh = hold + 0.01f * tanhf(acc[mi][nj][r] * INV);
        if (has_eps) {
          float e = fminf(fmaxf(ev[r], 0.f), 0.1f);
          nh = e * nh;
        }
        pv[r] = f2bf(nh);
        hout[idx] = pv[r];
      }
      if (mk_hw) {
        u64 pk = (u64)pv[0] | ((u64)pv[1] << 16) | ((u64)pv[2] << 32) | ((u64)pv[3] << 48);
        *(u64*)&gN[nl * 136 + dBase + j0] = pk;
      }
    }

  // copy untouched half to hout; also scatter into gN[n][oh+row]
  {
    int oh = (1 - half) * 64;
    const u16* src = hin + (size_t)(b * 128 + oh) * 2048 + n0;
    u16* dst = hout + (size_t)(b * 128 + oh) * 2048 + n0;
#pragma unroll
    for (int i = 0; i < 4; ++i) {
      int idx = i * 256 + tid;
      int rr = idx >> 4;
      int cc = (idx & 15) * 8;
      uint4 v = *(const uint4*)&src[(size_t)rr * 2048 + cc];
      *(uint4*)&dst[(size_t)rr * 2048 + cc] = v;
      if (mk_hw) {
        u16 t[8];
        *(uint4*)t = v;
#pragma unroll
        for (int q = 0; q < 8; ++q) gN[(cc + q) * 136 + oh + rr] = t[q];
      }
    }
  }

  if (mk_hw) {
    __syncthreads();
    // next hW: out[j'][n] = fp8( sum_d WnT[j'][d] * gN[n][d] )  (bf16 MFMA)
    f4 acc2[4][2] = {};
#pragma unroll
    for (int ks = 0; ks < 4; ++ks) {
      bf8 aw[4], bg[2];
#pragma unroll
      for (int mi = 0; mi < 4; ++mi)
        aw[mi] = *(const bf8*)&WnT[(size_t)(mi * 16 + col) * 128 + ks * 32 + quad * 8];
#pragma unroll
      for (int nj = 0; nj < 2; ++nj)
        bg[nj] = *(const bf8*)&gN[(wave * 32 + nj * 16 + col) * 136 + ks * 32 + quad * 8];
#pragma unroll
      for (int mi = 0; mi < 4; ++mi)
#pragma unroll
        for (int nj = 0; nj < 2; ++nj)
          acc2[mi][nj] = __builtin_amdgcn_mfma_f32_16x16x32_bf16(aw[mi], bg[nj], acc2[mi][nj], 0, 0, 0);
    }
#pragma unroll
    for (int mi = 0; mi < 4; ++mi)
#pragma unroll
      for (int nj = 0; nj < 2; ++nj) {
        int jp0 = mi * 16 + quad * 4;
        int n = n0 + wave * 32 + nj * 16 + col;
#pragma unroll
        for (int r = 0; r < 4; ++r)
          hWout[(size_t)(b * 64 + jp0 + r) * 2048 + n] = f2fp8(acc2[mi][nj][r]);
      }
  }
}

// ---------------- final un-transpose: out[b][n][d] = hT[(b*128+d)][n] ----------------
__global__ void untranspose(const u16* __restrict__ hT, void* __restrict__ out,
                            const u32* __restrict__ flag) {
  __shared__ __align__(16) u16 t[64][65];
  u32 isf32 = flag[0];
  int b = blockIdx.z, d0 = blockIdx.y * 64, n0 = blockIdx.x * 64;
  int tid = threadIdx.x;
#pragma unroll
  for (int i = 0; i < 16; ++i) {
    int idx = tid + i * 256;
    int r = idx >> 6, c = idx & 63;
    t[r][c] = hT[(size_t)(b * 128 + d0 + r) * 2048 + n0 + c];
  }
  __syncthreads();
#pragma unroll
  for (int i = 0; i < 16; ++i) {
    int idx = tid + i * 256;
    int r = idx >> 6, c = idx & 63;  // r = n-local, c = d-local
    size_t o = (size_t)(b * 2048 + n0 + r) * 128 + d0 + c;
    if (isf32) ((float*)out)[o] = bf2f(t[c][r]);
    else       ((u16*)out)[o] = t[c][r];
  }
}

extern "C" void kernel_launch(void* const* d_in, const int* in_sizes, int n_in,
                              void* d_out, int out_size, void* d_ws, size_t ws_size,
                              hipStream_t stream) {
  const void* x   = d_in[0];
  const void* hz  = d_in[1];
  const void* adj = d_in[2];
  const void* W1  = d_in[3];
  const void* W2  = d_in[4];
  const void* Wa  = d_in[5];
  const void* ba  = d_in[6];
  const void* Wb  = d_in[7];
  const void* bb  = d_in[8];
  const void* eps = d_in[9];

  // workspace layout (44.3 MB):
  //   hA   @  0M   16.78 MB  transposed h ping buffer (bf16 [4096][2048])
  //   adj8 @ 17M    4.19 MB  adj fp8 x2^16 [2048][2048]
  //   hWa  @ 26M    4.19 MB  hW ping (fp8 [2048][2048])
  //   hWb  @ 35M    4.19 MB  hW pong
  //   weights @ 44M (229 KB), flag after
  // hB (pong h) = d_out scratch; untranspose fully rewrites d_out at the end.
  char* ws = (char*)d_ws;
  u16* hA   = (u16*)(ws);
  u8*  adj8 = (u8*)(ws + (17ull << 20));
  u8*  hWa  = (u8*)(ws + (26ull << 20));
  u8*  hWb  = (u8*)(ws + (35ull << 20));
  u16* WaT  = (u16*)(ws + (44ull << 20));
  u16* WbT  = WaT + 256 * 256;
  u16* W1T  = WbT + 128 * 256;
  u16* W2T  = W1T + 64 * 128;
  u32* flag = (u32*)(W2T + 64 * 128);
  u16* hB   = (u16*)d_out;

  detect_dtype<<<dim3(1), dim3(256), 0, stream>>>((const u16*)x, flag);
  prep_weights<<<dim3(448), dim3(256), 0, stream>>>(Wa, Wb, W1, W2, WaT, WbT, W1T, W2T, flag);
  cvt_fp8<<<dim3(4096), dim3(256), 0, stream>>>(adj, adj8, 4194304, flag);
  mlp_fused<<<dim3(1024), dim3(256), 0, stream>>>(x, hz, WaT, ba, WbT, bb, W1T, hA, hWa, flag);
  // step 1 (half=0, consumes hWa=h0@W1h, produces hWb=h1@W2h)
  fused_step2<<<dim3(16, 32), dim3(256), 0, stream>>>(hA, hWa, adj8, W2T, nullptr, hB, hWb, 0, flag);
  // step 2 (half=1, eps; consumes hWb, produces hWa=h2@W1h)
  fused_step2<<<dim3(16, 32), dim3(256), 0, stream>>>(hB, hWb, adj8, W1T, eps, hA, hWa, 1, flag);
  // step 3 (half=0; consumes hWa, produces hWb=h3@W2h)
  fused_step2<<<dim3(16, 32), dim3(256), 0, stream>>>(hA, hWa, adj8, W2T, nullptr, hB, hWb, 0, flag);
  // step 4 (half=1, eps; consumes hWb, no next hW)
  fused_step2<<<dim3(16, 32), dim3(256), 0, stream>>>(hB, hWb, adj8, nullptr, eps, hA, nullptr, 1, flag);
  untranspose<<<dim3(32, 2, 32), dim3(256), 0, stream>>>(hA, d_out, flag);
}

// Round 7
// 410.333 us; speedup vs baseline: 1.0650x; 1.0650x over previous
//
#include <hip/hip_runtime.h>

// GODE on MI355X. bf16/fp8 MFMA, fp32 accum, h TRANSPOSED: hT[(b*128+d)][n].
// R5 algebra: (adj@h)@W_half == adj@(h@W_half)  -> big GEMM per step is
// [64 j x 2048 n2, K=2048] per batch, operands hW8[(b*64+j)][n], adj8[n2][n]
// (fp8 e4m3; adj pre-scaled x2^16, C rescaled before tanh — R10, verified).
// R12: fs2 cross-round invariant: ~70us regardless of dtype/BK/staging/sync
// -> latency-bound with compute-per-iter << drain latency and only 2 resident
// blocks/CU (grid 512, LDS >= 34.8KB). Fix: 64x64 tiles -> grid 1024
// (4/CU resident, 5 allowed by 32KB LDS), gN shrinks to 17.4KB, staging in
// R10's proven coalesced fp8 subtile layout, BK=256. Bijective XCD swizzle:
// each XCD owns 4 whole batches (A panels L2-resident). mlp: R10 proven
// version verbatim (R11's quad-major staging = global scatter-gather; reverted).

typedef unsigned short u16;
typedef unsigned char  u8;
typedef unsigned int   u32;
typedef unsigned long long u64;
typedef __attribute__((ext_vector_type(8))) short bf8;  // 8 raw bf16 (4 VGPRs)
typedef __attribute__((ext_vector_type(4))) float f4;

#define AS1 __attribute__((address_space(1)))
#define AS3 __attribute__((address_space(3)))

__device__ __forceinline__ void gl_lds16(const void* g, void* l) {
  __builtin_amdgcn_global_load_lds((const AS1 u32*)g, (AS3 u32*)l, 16, 0, 0);
}
__device__ __forceinline__ float bf2f(u16 v) {
  u32 u = ((u32)v) << 16; return __builtin_bit_cast(float, u);
}
__device__ __forceinline__ u16 f2bf(float f) {  // RNE
  u32 u = __builtin_bit_cast(u32, f);
  return (u16)((u + 0x7fffu + ((u >> 16) & 1u)) >> 16);
}
// software float -> OCP e4m3 (RNE, saturate to 448, no inf)
__device__ __forceinline__ u8 f2fp8(float f) {
  u32 u = __builtin_bit_cast(u32, f);
  u32 s = (u >> 24) & 0x80u;
  int e = (int)((u >> 23) & 0xFFu) - 127;
  u32 m = u & 0x7FFFFFu;
  if (e > 8 || (e == 8 && m >= 0x700000u)) return (u8)(s | 0x7Eu);  // clamp 448
  if (e >= -6) {
    u32 keep = m >> 20, rest = m & 0xFFFFFu;
    keep += (rest > 0x80000u || (rest == 0x80000u && (keep & 1u))) ? 1u : 0u;
    u32 v = ((u32)(e + 7) << 3) + keep;       // mantissa carry rolls into exp
    if (v >= 0x7Fu) v = 0x7Eu;
    return (u8)(s | v);
  }
  if (e < -10) return (u8)s;                   // below half of min subnormal
  u32 mm = 0x800000u | m;
  int sh = 14 - e;                             // 21..24
  u32 q = mm >> sh, rem = mm & ((1u << sh) - 1u), half = 1u << (sh - 1);
  q += (rem > half || (rem == half && (q & 1u))) ? 1u : 0u;
  return (u8)(s | q);
}
__device__ __forceinline__ float ldf(const void* p, size_t i, u32 isf32) {
  return isf32 ? ((const float*)p)[i] : bf2f(((const u16*)p)[i]);
}

// ---- [rows][32] bf16 staging (R0-proven; 16 rows x 64B coalesced) ----
__device__ __forceinline__ void stage128x32(const u16* grow0, int stride, u16* lds,
                                            int wave, int lane) {
  int r0 = wave * 16 + (lane >> 2);
  int c0 = (lane & 3) * 8;
  gl_lds16(grow0 + (size_t)r0 * stride + c0, lds + wave * 512);
  gl_lds16(grow0 + (size_t)(64 + r0) * stride + c0, lds + 2048 + wave * 512);
}

// ---------------- dtype detection ----------------
__global__ void detect_dtype(const u16* __restrict__ x_raw, u32* __restrict__ flag) {
  __shared__ int s;
  int tid = threadIdx.x;
  if (tid == 0) s = 0;
  __syncthreads();
  int huge = 0;
#pragma unroll
  for (int j = 0; j < 16; ++j) {
    u16 v = x_raw[tid * 16 + j];
    u32 e = (v >> 7) & 0xFF;
    if (e >= 0xC0) huge = 1;          // |v| >= 2^64: impossible for N(0,1) bf16
  }
  if (huge) atomicOr(&s, 1);
  __syncthreads();
  if (tid == 0) flag[0] = (u32)s;     // 1 = f32 inputs, 0 = bf16 inputs
}

// ---------------- adj -> fp8 (x 2^16) ----------------
__global__ void cvt_fp8(const void* __restrict__ in, u8* __restrict__ out,
                        int n, const u32* __restrict__ flag) {
  u32 isf32 = flag[0];
  int gid = blockIdx.x * 256 + threadIdx.x;
  if (gid * 4 >= n) return;
  size_t i = (size_t)gid * 4;
  u32 pk = 0;
#pragma unroll
  for (int j = 0; j < 4; ++j)
    pk |= (u32)f2fp8(ldf(in, i + j, isf32) * 65536.0f) << (8 * j);
  *(u32*)&out[i] = pk;
}

// ---------------- weight pre-transpose ----------------
// WaT[256][256]=Wa^T, WbT[128][256]=Wb^T, W1T[64][128]=W1[:, :64]^T, W2T[64][128]=W2[:, 64:]^T
__global__ void prep_weights(const void* __restrict__ Wa, const void* __restrict__ Wb,
                             const void* __restrict__ W1, const void* __restrict__ W2,
                             u16* __restrict__ WaT, u16* __restrict__ WbT,
                             u16* __restrict__ W1T, u16* __restrict__ W2T,
                             const u32* __restrict__ flag) {
  u32 isf32 = flag[0];
  int i = blockIdx.x * 256 + threadIdx.x;
  if (i < 65536) {
    int o = i >> 8, k = i & 255; WaT[o * 256 + k] = f2bf(ldf(Wa, (size_t)k * 256 + o, isf32));
  } else if (i < 98304) {
    int j = i - 65536; int o = j >> 8, k = j & 255;
    WbT[o * 256 + k] = f2bf(ldf(Wb, (size_t)k * 128 + o, isf32));
  } else if (i < 106496) {
    int j = i - 98304; int jj = j >> 7, k = j & 127;
    W1T[jj * 128 + k] = f2bf(ldf(W1, (size_t)k * 128 + jj, isf32));
  } else {
    int j = i - 106496; int jj = j >> 7, k = j & 127;
    W2T[jj * 128 + k] = f2bf(ldf(W2, (size_t)k * 128 + 64 + jj, isf32));
  }
}

// ---------------- fused MLP + first hW (R0 structure, proven) ----------------
// hT = tanh(relu([x,hz]@Wa+ba)@Wb+bb)  (transposed store), and
// hW1[(b*64+j)][n] = fp8( sum_d W1T[j][d] * h0[n-row][d] ).
__global__ __launch_bounds__(256, 2) void mlp_fused(const void* __restrict__ x,
                                                    const void* __restrict__ hz,
                                                    const u16* __restrict__ WaT,
                                                    const void* __restrict__ ba,
                                                    const u16* __restrict__ WbT,
                                                    const void* __restrict__ bb,
                                                    const u16* __restrict__ W1T,
                                                    u16* __restrict__ hT,
                                                    u8* __restrict__ hW,
                                                    const u32* __restrict__ flag) {
  __shared__ __align__(16) u16 Z[64 * 264];     // 33.8 KB
  __shared__ __align__(16) u16 pool[10240];     // 20 KB: lA 64x32 | lB 256x32; later hN 64x136
  u16* lA = pool;
  u16* lB = pool + 2048;
  u16* hN = pool;                               // 64*136 = 8704 u16, overlays lA/lB post-use
  u32 isf32 = flag[0];
  int tid = threadIdx.x, lane = tid & 63, wave = tid >> 6;
  int col = lane & 15, quad = lane >> 4;
  int r0 = blockIdx.x * 64;
  int b = r0 >> 11;

  // phase 1: Z = relu(u @ Wa + ba), u = [x|hz], tile 64 x 256 (waves split 256 o-cols)
  f4 acc[4][4] = {};
  for (int kk = 0; kk < 8; ++kk) {
    int k0 = kk * 32;
    const void* src = (kk < 4) ? x : hz;
    int csrc = (kk < 4) ? k0 : (k0 - 128);
    __syncthreads();
    {  // stage A 64x32 with dtype convert
      int row = tid >> 2, c0 = (tid & 3) * 8;
      size_t g = (size_t)(r0 + row) * 128 + csrc + c0;
      uint4 pk;
      if (isf32) {
        f4 v0 = *(const f4*)&((const float*)src)[g];
        f4 v1 = *(const f4*)&((const float*)src)[g + 4];
        pk.x = (u32)f2bf(v0[0]) | ((u32)f2bf(v0[1]) << 16);
        pk.y = (u32)f2bf(v0[2]) | ((u32)f2bf(v0[3]) << 16);
        pk.z = (u32)f2bf(v1[0]) | ((u32)f2bf(v1[1]) << 16);
        pk.w = (u32)f2bf(v1[2]) | ((u32)f2bf(v1[3]) << 16);
      } else {
        pk = *(const uint4*)&((const u16*)src)[g];
      }
      *(uint4*)&lA[row * 32 + c0] = pk;
    }
    stage128x32(WaT + k0, 256, lB, wave, lane);
    stage128x32(WaT + (size_t)128 * 256 + k0, 256, lB + 4096, wave, lane);
    __syncthreads();
    bf8 af[4], bfr[4];
#pragma unroll
    for (int mi = 0; mi < 4; ++mi) af[mi] = *(const bf8*)&lA[(mi * 16 + col) * 32 + quad * 8];
#pragma unroll
    for (int nj = 0; nj < 4; ++nj) bfr[nj] = *(const bf8*)&lB[(wave * 64 + nj * 16 + col) * 32 + quad * 8];
#pragma unroll
    for (int mi = 0; mi < 4; ++mi)
#pragma unroll
      for (int nj = 0; nj < 4; ++nj)
        acc[mi][nj] = __builtin_amdgcn_mfma_f32_16x16x32_bf16(af[mi], bfr[nj], acc[mi][nj], 0, 0, 0);
  }
#pragma unroll
  for (int mi = 0; mi < 4; ++mi)
#pragma unroll
    for (int nj = 0; nj < 4; ++nj) {
      int o = wave * 64 + nj * 16 + col;
      float bav = ldf(ba, o, isf32);
      int rl = mi * 16 + quad * 4;
#pragma unroll
      for (int r = 0; r < 4; ++r)
        Z[(rl + r) * 264 + o] = f2bf(fmaxf(acc[mi][nj][r] + bav, 0.f));
    }
  __syncthreads();

  // phase 2: h0 = tanh(Z @ Wb + bb); A-frags from Z (stride 264)
  f4 acc2[4][2] = {};
  for (int kk = 0; kk < 8; ++kk) {
    int k0 = kk * 32;
    if (kk) __syncthreads();
    stage128x32(WbT + k0, 256, lB, wave, lane);
    __syncthreads();
    bf8 az[4], bw[2];
#pragma unroll
    for (int mi = 0; mi < 4; ++mi) az[mi] = *(const bf8*)&Z[(mi * 16 + col) * 264 + k0 + quad * 8];
#pragma unroll
    for (int nj = 0; nj < 2; ++nj) bw[nj] = *(const bf8*)&lB[(wave * 32 + nj * 16 + col) * 32 + quad * 8];
#pragma unroll
    for (int mi = 0; mi < 4; ++mi)
#pragma unroll
      for (int nj = 0; nj < 2; ++nj)
        acc2[mi][nj] = __builtin_amdgcn_mfma_f32_16x16x32_bf16(az[mi], bw[nj], acc2[mi][nj], 0, 0, 0);
  }
  __syncthreads();   // all waves done with lB before hN overlay

  // epilogue: tanh(+bb) -> global hT (transposed) AND hN[r][d] staging for hW1
#pragma unroll
  for (int mi = 0; mi < 4; ++mi)
#pragma unroll
    for (int nj = 0; nj < 2; ++nj) {
      int d = wave * 32 + nj * 16 + col;
      float bbv = ldf(bb, d, isf32);
      int rl = mi * 16 + quad * 4;
      int rabs = r0 + rl;
      int n = rabs & 2047;
      u16 p[4];
#pragma unroll
      for (int r = 0; r < 4; ++r) {
        p[r] = f2bf(tanhf(acc2[mi][nj][r] + bbv));
        hN[(rl + r) * 136 + d] = p[r];
      }
      u64 pk = (u64)p[0] | ((u64)p[1] << 16) | ((u64)p[2] << 32) | ((u64)p[3] << 48);
      *(u64*)&hT[(size_t)(b * 128 + d) * 2048 + n] = pk;
    }
  __syncthreads();

  // hW1: out[j][r] = sum_d W1T[j][d] * hN[r][d]; wave covers r in [wave*16, wave*16+16)
  f4 acc3[4] = {};
#pragma unroll
  for (int ks = 0; ks < 4; ++ks) {
    bf8 aw[4], bg;
#pragma unroll
    for (int mi = 0; mi < 4; ++mi)
      aw[mi] = *(const bf8*)&W1T[(size_t)(mi * 16 + col) * 128 + ks * 32 + quad * 8];
    bg = *(const bf8*)&hN[(wave * 16 + col) * 136 + ks * 32 + quad * 8];
#pragma unroll
    for (int mi = 0; mi < 4; ++mi)
      acc3[mi] = __builtin_amdgcn_mfma_f32_16x16x32_bf16(aw[mi], bg, acc3[mi], 0, 0, 0);
  }
#pragma unroll
  for (int mi = 0; mi < 4; ++mi) {
    int rloc = wave * 16 + col;
    int ng = (r0 & 2047) + rloc;
#pragma unroll
    for (int r = 0; r < 4; ++r) {
      int j = mi * 16 + quad * 4 + r;
      hW[(size_t)(b * 64 + j) * 2048 + ng] = f2fp8(acc3[mi][r]);
    }
  }
}

// ---------------- fused diffusion step (v9: 64x64 tiles, 1024 blocks) ----
// Big GEMM (fp8): G[m=(b,j)][n2] = sum_n hW8[(b*64+j)][n] * adj8[n2][n],
// C = acc * 2^-16. Tile 64x64, 4 waves (wave w: all 64 m x n-slice w*16..+16).
// BK=256, 8 iters; LDS = 32KB staging (A 16KB + B 16KB, fp8 subtile layout:
// 1KB = 32 rows x 32 k, cells [kh2][row32][16B], coalesced 32B row-segments),
// gN [64][136] bf16 = 17.4KB overlays. 1024 blocks -> 4 resident/CU (5 by
// LDS): blocks mutually hide stage/drain latency. Bijective XCD swizzle:
// XCD k owns batches 4k..4k+3 entirely (A panels + hin rows L2-local).
__global__ __launch_bounds__(256, 4) void fused_step2(const u16* __restrict__ hin,
                                                      const u8* __restrict__ hW8,
                                                      const u8* __restrict__ adj8,
                                                      const u16* __restrict__ WnT,
                                                      const void* __restrict__ eps,
                                                      u16* __restrict__ hout,
                                                      u8* __restrict__ hWout,
                                                      int half, const u32* __restrict__ flag) {
  __shared__ __align__(16) u16 smem[16384];   // 32 KB: lA8 16KB | lB8 16KB; gN overlays
  u8* lA8 = (u8*)smem;
  u8* lB8 = lA8 + 16384;
  u16* gN = smem;               // [64][136] = 8704 u16, overlays post K-loop
  u32 isf32 = flag[0];
  int tid = threadIdx.x, lane = tid & 63, wave = tid >> 6;
  int col = lane & 15, quad = lane >> 4;

  // bijective swizzle over 1024 blocks: XCD (bid%8) gets 128 consecutive work
  // items = 4 whole batches (A panel 128KB x4 + hin rows L2-local per XCD).
  int bid = blockIdx.y * 32 + blockIdx.x;
  int sw = (bid & 7) * 128 + (bid >> 3);
  int b = sw >> 5;
  int n0 = (sw & 31) * 64;

  const u8* Arow = hW8 + (size_t)(b * 64) * 2048;
  const u8* Brow = adj8 + (size_t)n0 * 2048;
  int r32 = lane & 31, kh16 = (lane >> 5) * 16;
  int baseQ = (quad >> 1) * 512 + (quad & 1) * 8 + col * 16;

  f4 acc[4] = {};
#pragma unroll 1
  for (int ch = 0; ch < 8; ++ch) {
    {  // stage A 16 + B 16 subtiles; wave stages 4 A + 4 B (8 gl_lds)
      int g = wave >> 1, kc0 = (wave & 1) * 4;
      const u8* As = Arow + (size_t)(g * 32 + r32) * 2048 + ch * 256 + kh16;
      const u8* Bs = Brow + (size_t)(g * 32 + r32) * 2048 + ch * 256 + kh16;
      u8* Ad = lA8 + g * 8192 + kc0 * 1024;
      u8* Bd = lB8 + g * 8192 + kc0 * 1024;
#pragma unroll
      for (int q = 0; q < 4; ++q) {
        gl_lds16(As + (kc0 + q) * 32, Ad + q * 1024);
        gl_lds16(Bs + (kc0 + q) * 32, Bd + q * 1024);
      }
    }
    __syncthreads();
#pragma unroll
    for (int ks = 0; ks < 8; ++ks) {
      long long af[4], bfr;
      bfr = *(const long long*)&lB8[(wave >> 1) * 8192 + ks * 1024 + (wave & 1) * 256 + baseQ];
#pragma unroll
      for (int mi = 0; mi < 4; ++mi)
        af[mi] = *(const long long*)&lA8[(mi >> 1) * 8192 + ks * 1024 + (mi & 1) * 256 + baseQ];
#pragma unroll
      for (int mi = 0; mi < 4; ++mi)
        acc[mi] = __builtin_amdgcn_mfma_f32_16x16x32_fp8_fp8(af[mi], bfr, acc[mi], 0, 0, 0);
    }
    __syncthreads();
  }

  bool has_eps = (eps != nullptr);
  bool mk_hw = (WnT != nullptr);
  int dBase = half * 64;
  const float INV = 1.52587890625e-05f;   // 2^-16 (adj pre-scale)
  int nl = wave * 16 + col;
  int n = n0 + nl;
  // update + write updated half; stage nh into gN[n][dBase+j]
#pragma unroll
  for (int mi = 0; mi < 4; ++mi) {
    int j0 = mi * 16 + quad * 4;
    float ev[4];
    if (has_eps) {
      size_t eoff = ((size_t)b * 2048 + n) * 64 + j0;
      if (isf32) {
        f4 e = *(const f4*)&((const float*)eps)[eoff];
        ev[0] = e[0]; ev[1] = e[1]; ev[2] = e[2]; ev[3] = e[3];
      } else {
        u64 e = *(const u64*)&((const u16*)eps)[eoff];
        ev[0] = bf2f((u16)e); ev[1] = bf2f((u16)(e >> 16));
        ev[2] = bf2f((u16)(e >> 32)); ev[3] = bf2f((u16)(e >> 48));
      }
    }
    u16 pv[4];
#pragma unroll
    for (int r = 0; r < 4; ++r) {
      int j = j0 + r;
      size_t idx = (size_t)(b * 128 + dBase + j) * 2048 + n;
      float hold = bf2f(hin[idx]);
      float nh = hold + 0.01f * tanhf(acc[mi][r] * INV);
      if (has_eps) {
        float e = fminf(fmaxf(ev[r], 0.f), 0.1f);
        nh = e * nh;
      }
      pv[r] = f2bf(nh);
      hout[idx] = pv[r];
    }
    if (mk_hw) {
      u64 pk = (u64)pv[0] | ((u64)pv[1] << 16) | ((u64)pv[2] << 32) | ((u64)pv[3] << 48);
      *(u64*)&gN[nl * 136 + dBase + j0] = pk;
    }
  }

  // copy untouched half (64 d-rows x 64 n) to hout; scatter into gN[n][oh+row]
  {
    int oh = (1 - half) * 64;
    const u16* src = hin + (size_t)(b * 128 + oh) * 2048 + n0;
    u16* dst = hout + (size_t)(b * 128 + oh) * 2048 + n0;
#pragma unroll
    for (int i = 0; i < 2; ++i) {
      int idx = i * 256 + tid;          // [0, 512)
      int rr = idx >> 3;                // d-row 0..63
      int cc = (idx & 7) * 8;           // n-col 0..56
      uint4 v = *(const uint4*)&src[(size_t)rr * 2048 + cc];
      *(uint4*)&dst[(size_t)rr * 2048 + cc] = v;
      if (mk_hw) {
        u16 t[8];
        *(uint4*)t = v;
#pragma unroll
        for (int q = 0; q < 8; ++q) gN[(cc + q) * 136 + oh + rr] = t[q];
      }
    }
  }

  if (mk_hw) {
    __syncthreads();
    // next hW: out[j'][n] = fp8( sum_d WnT[j'][d] * gN[n][d] )  (bf16 MFMA)
    f4 acc2[4] = {};
#pragma unroll
    for (int ks = 0; ks < 4; ++ks) {
      bf8 aw[4], bg;
#pragma unroll
      for (int mi = 0; mi < 4; ++mi)
        aw[mi] = *(const bf8*)&WnT[(size_t)(mi * 16 + col) * 128 + ks * 32 + quad * 8];
      bg = *(const bf8*)&gN[(wave * 16 + col) * 136 + ks * 32 + quad * 8];
#pragma unroll
      for (int mi = 0; mi < 4; ++mi)
        acc2[mi] = __builtin_amdgcn_mfma_f32_16x16x32_bf16(aw[mi], bg, acc2[mi], 0, 0, 0);
    }
#pragma unroll
    for (int mi = 0; mi < 4; ++mi) {
      int jp0 = mi * 16 + quad * 4;
      int ng = n0 + wave * 16 + col;
#pragma unroll
      for (int r = 0; r < 4; ++r)
        hWout[(size_t)(b * 64 + jp0 + r) * 2048 + ng] = f2fp8(acc2[mi][r]);
    }
  }
}

// ---------------- final un-transpose: out[b][n][d] = hT[(b*128+d)][n] ----------------
__global__ void untranspose(const u16* __restrict__ hT, void* __restrict__ out,
                            const u32* __restrict__ flag) {
  __shared__ __align__(16) u16 t[64][65];
  u32 isf32 = flag[0];
  int b = blockIdx.z, d0 = blockIdx.y * 64, n0 = blockIdx.x * 64;
  int tid = threadIdx.x;
#pragma unroll
  for (int i = 0; i < 16; ++i) {
    int idx = tid + i * 256;
    int r = idx >> 6, c = idx & 63;
    t[r][c] = hT[(size_t)(b * 128 + d0 + r) * 2048 + n0 + c];
  }
  __syncthreads();
#pragma unroll
  for (int i = 0; i < 16; ++i) {
    int idx = tid + i * 256;
    int r = idx >> 6, c = idx & 63;  // r = n-local, c = d-local
    size_t o = (size_t)(b * 2048 + n0 + r) * 128 + d0 + c;
    if (isf32) ((float*)out)[o] = bf2f(t[c][r]);
    else       ((u16*)out)[o] = t[c][r];
  }
}

extern "C" void kernel_launch(void* const* d_in, const int* in_sizes, int n_in,
                              void* d_out, int out_size, void* d_ws, size_t ws_size,
                              hipStream_t stream) {
  const void* x   = d_in[0];
  const void* hz  = d_in[1];
  const void* adj = d_in[2];
  const void* W1  = d_in[3];
  const void* W2  = d_in[4];
  const void* Wa  = d_in[5];
  const void* ba  = d_in[6];
  const void* Wb  = d_in[7];
  const void* bb  = d_in[8];
  const void* eps = d_in[9];

  // workspace layout (44.3 MB):
  //   hA   @  0M   16.78 MB  transposed h ping buffer (bf16 [4096][2048])
  //   adj8 @ 17M    4.19 MB  adj fp8 x2^16 [2048][2048]
  //   hWa  @ 26M    4.19 MB  hW ping (fp8 [2048][2048])
  //   hWb  @ 35M    4.19 MB  hW pong
  //   weights @ 44M (229 KB), flag after
  // hB (pong h) = d_out scratch; untranspose fully rewrites d_out at the end.
  char* ws = (char*)d_ws;
  u16* hA   = (u16*)(ws);
  u8*  adj8 = (u8*)(ws + (17ull << 20));
  u8*  hWa  = (u8*)(ws + (26ull << 20));
  u8*  hWb  = (u8*)(ws + (35ull << 20));
  u16* WaT  = (u16*)(ws + (44ull << 20));
  u16* WbT  = WaT + 256 * 256;
  u16* W1T  = WbT + 128 * 256;
  u16* W2T  = W1T + 64 * 128;
  u32* flag = (u32*)(W2T + 64 * 128);
  u16* hB   = (u16*)d_out;

  detect_dtype<<<dim3(1), dim3(256), 0, stream>>>((const u16*)x, flag);
  prep_weights<<<dim3(448), dim3(256), 0, stream>>>(Wa, Wb, W1, W2, WaT, WbT, W1T, W2T, flag);
  cvt_fp8<<<dim3(4096), dim3(256), 0, stream>>>(adj, adj8, 4194304, flag);
  mlp_fused<<<dim3(1024), dim3(256), 0, stream>>>(x, hz, WaT, ba, WbT, bb, W1T, hA, hWa, flag);
  // step 1 (half=0, consumes hWa=h0@W1h, produces hWb=h1@W2h)
  fused_step2<<<dim3(32, 32), dim3(256), 0, stream>>>(hA, hWa, adj8, W2T, nullptr, hB, hWb, 0, flag);
  // step 2 (half=1, eps; consumes hWb, produces hWa=h2@W1h)
  fused_step2<<<dim3(32, 32), dim3(256), 0, stream>>>(hB, hWb, adj8, W1T, eps, hA, hWa, 1, flag);
  // step 3 (half=0; consumes hWa, produces hWb=h3@W2h)
  fused_step2<<<dim3(32, 32), dim3(256), 0, stream>>>(hA, hWa, adj8, W2T, nullptr, hB, hWb, 0, flag);
  // step 4 (half=1, eps; consumes hWb, no next hW)
  fused_step2<<<dim3(32, 32), dim3(256), 0, stream>>>(hB, hWb, adj8, nullptr, eps, hA, nullptr, 1, flag);
  untranspose<<<dim3(32, 2, 32), dim3(256), 0, stream>>>(hA, d_out, flag);
}

// Round 8
// 357.013 us; speedup vs baseline: 1.2240x; 1.1493x over previous
//
#include <hip/hip_runtime.h>

// GODE on MI355X. bf16 MFMA, fp32 accum, h TRANSPOSED: hT[(b*128+d)][n].
// R5 algebra: (adj@h)@W_half == adj@(h@W_half)  -> big GEMM per step is
// [64 j x 2048 n2, K=2048] per batch. hW (h@W_half, transposed layout
// hWT[(b*64+j)][n], [2048][2048]) is produced in the PREVIOUS kernel's
// epilogue via the proven in-LDS pass-2 structure. Big-GEMM K-loop uses
// BK=128 (4x 32-col panels, [rows][32] LDS layout each).
// R13: back to the R0 chassis verbatim (only measured-best structure; R6-R12
// structural variants were all neutral-to-worse, and R10-vs-R12 proved
// cross-run clock variance makes small cross-round deltas unreadable).
// Single work-reducing change: untranspose is FUSED into step 4's epilogue —
// gN[n][d] (already the transposed layout, already written by the mk_hw code
// path) is staged in step 4 too, then written straight to d_out with
// coalesced 512B rows. Deletes the untranspose kernel (50 MB traffic +
// launch) and step 4's 16.8 MB hout write. h ping-pong flipped (mlp->hB=d_out)
// so step 4 reads hA (workspace) while writing d_out: no overlap.

typedef unsigned short u16;
typedef unsigned int   u32;
typedef unsigned long long u64;
typedef __attribute__((ext_vector_type(8))) short bf8;  // 8 raw bf16 (4 VGPRs)
typedef __attribute__((ext_vector_type(4))) float f4;

#define AS1 __attribute__((address_space(1)))
#define AS3 __attribute__((address_space(3)))

__device__ __forceinline__ void gl_lds16(const void* g, void* l) {
  __builtin_amdgcn_global_load_lds((const AS1 u32*)g, (AS3 u32*)l, 16, 0, 0);
}
__device__ __forceinline__ float bf2f(u16 v) {
  u32 u = ((u32)v) << 16; return __builtin_bit_cast(float, u);
}
__device__ __forceinline__ u16 f2bf(float f) {  // RNE
  u32 u = __builtin_bit_cast(u32, f);
  return (u16)((u + 0x7fffu + ((u >> 16) & 1u)) >> 16);
}
__device__ __forceinline__ float ldf(const void* p, size_t i, u32 isf32) {
  return isf32 ? ((const float*)p)[i] : bf2f(((const u16*)p)[i]);
}

// Stage 128x32 bf16 tile (row stride `stride`) into LDS [128][32]; 2 calls/wave.
__device__ __forceinline__ void stage128x32(const u16* grow0, int stride, u16* lds,
                                            int wave, int lane) {
  int r0 = wave * 16 + (lane >> 2);
  int c0 = (lane & 3) * 8;
  gl_lds16(grow0 + (size_t)r0 * stride + c0, lds + wave * 512);
  gl_lds16(grow0 + (size_t)(64 + r0) * stride + c0, lds + 2048 + wave * 512);
}
// Stage 64x32 tile into LDS [64][32]; 1 call/wave.
__device__ __forceinline__ void stage64x32(const u16* grow0, int stride, u16* lds,
                                           int wave, int lane) {
  gl_lds16(grow0 + (size_t)(wave * 16 + (lane >> 2)) * stride + (lane & 3) * 8,
           lds + wave * 512);
}

// ---------------- dtype detection ----------------
__global__ void detect_dtype(const u16* __restrict__ x_raw, u32* __restrict__ flag) {
  __shared__ int s;
  int tid = threadIdx.x;
  if (tid == 0) s = 0;
  __syncthreads();
  int huge = 0;
#pragma unroll
  for (int j = 0; j < 16; ++j) {
    u16 v = x_raw[tid * 16 + j];
    u32 e = (v >> 7) & 0xFF;
    if (e >= 0xC0) huge = 1;          // |v| >= 2^64: impossible for N(0,1) bf16
  }
  if (huge) atomicOr(&s, 1);
  __syncthreads();
  if (tid == 0) flag[0] = (u32)s;     // 1 = f32 inputs, 0 = bf16 inputs
}

// ---------------- generic convert to bf16 (adj) ----------------
__global__ void cvt_bf16(const void* __restrict__ in, u16* __restrict__ out,
                         long in_off, int n, const u32* __restrict__ flag) {
  u32 isf32 = flag[0];
  int gid = blockIdx.x * 256 + threadIdx.x;
  long i = in_off + (long)gid * 4;
  if (gid * 4 >= n) return;
  u16 o0, o1, o2, o3;
  if (isf32) {
    f4 v = *(const f4*)&((const float*)in)[i];
    o0 = f2bf(v[0]); o1 = f2bf(v[1]); o2 = f2bf(v[2]); o3 = f2bf(v[3]);
  } else {
    u64 v = *(const u64*)&((const u16*)in)[i];
    o0 = (u16)v; o1 = (u16)(v >> 16); o2 = (u16)(v >> 32); o3 = (u16)(v >> 48);
  }
  u64 pk = (u64)o0 | ((u64)o1 << 16) | ((u64)o2 << 32) | ((u64)o3 << 48);
  *(u64*)&out[(size_t)gid * 4] = pk;
}

// ---------------- weight pre-transpose ----------------
// WaT[256][256]=Wa^T, WbT[128][256]=Wb^T, W1T[64][128]=W1[:, :64]^T, W2T[64][128]=W2[:, 64:]^T
__global__ void prep_weights(const void* __restrict__ Wa, const void* __restrict__ Wb,
                             const void* __restrict__ W1, const void* __restrict__ W2,
                             u16* __restrict__ WaT, u16* __restrict__ WbT,
                             u16* __restrict__ W1T, u16* __restrict__ W2T,
                             const u32* __restrict__ flag) {
  u32 isf32 = flag[0];
  int i = blockIdx.x * 256 + threadIdx.x;
  if (i < 65536) {
    int o = i >> 8, k = i & 255; WaT[o * 256 + k] = f2bf(ldf(Wa, (size_t)k * 256 + o, isf32));
  } else if (i < 98304) {
    int j = i - 65536; int o = j >> 8, k = j & 255;
    WbT[o * 256 + k] = f2bf(ldf(Wb, (size_t)k * 128 + o, isf32));
  } else if (i < 106496) {
    int j = i - 98304; int jj = j >> 7, k = j & 127;
    W1T[jj * 128 + k] = f2bf(ldf(W1, (size_t)k * 128 + jj, isf32));
  } else {
    int j = i - 106496; int jj = j >> 7, k = j & 127;
    W2T[jj * 128 + k] = f2bf(ldf(W2, (size_t)k * 128 + 64 + jj, isf32));
  }
}

// ---------------- fused MLP + first hW ----------------
// hT = tanh(relu([x,hz]@Wa+ba)@Wb+bb)  (transposed store), and
// hW1T[(b*64+j)][n] = sum_d W1T[j][d] * h0[n-row][d]  (epilogue in-LDS GEMM).
__global__ __launch_bounds__(256, 2) void mlp_fused(const void* __restrict__ x,
                                                    const void* __restrict__ hz,
                                                    const u16* __restrict__ WaT,
                                                    const void* __restrict__ ba,
                                                    const u16* __restrict__ WbT,
                                                    const void* __restrict__ bb,
                                                    const u16* __restrict__ W1T,
                                                    u16* __restrict__ hT,
                                                    u16* __restrict__ hW,
                                                    const u32* __restrict__ flag) {
  __shared__ __align__(16) u16 Z[64 * 264];     // 33.8 KB
  __shared__ __align__(16) u16 pool[10240];     // 20 KB: lA 64x32 | lB 256x32; later hN 64x136
  u16* lA = pool;
  u16* lB = pool + 2048;
  u16* hN = pool;                               // 64*136 = 8704 u16, overlays lA/lB post-use
  u32 isf32 = flag[0];
  int tid = threadIdx.x, lane = tid & 63, wave = tid >> 6;
  int col = lane & 15, quad = lane >> 4;
  int r0 = blockIdx.x * 64;
  int b = r0 >> 11;

  // phase 1: Z = relu(u @ Wa + ba), u = [x|hz], tile 64 x 256 (waves split 256 o-cols)
  f4 acc[4][4] = {};
  for (int kk = 0; kk < 8; ++kk) {
    int k0 = kk * 32;
    const void* src = (kk < 4) ? x : hz;
    int csrc = (kk < 4) ? k0 : (k0 - 128);
    __syncthreads();
    {  // stage A 64x32 with dtype convert
      int row = tid >> 2, c0 = (tid & 3) * 8;
      size_t g = (size_t)(r0 + row) * 128 + csrc + c0;
      uint4 pk;
      if (isf32) {
        f4 v0 = *(const f4*)&((const float*)src)[g];
        f4 v1 = *(const f4*)&((const float*)src)[g + 4];
        pk.x = (u32)f2bf(v0[0]) | ((u32)f2bf(v0[1]) << 16);
        pk.y = (u32)f2bf(v0[2]) | ((u32)f2bf(v0[3]) << 16);
        pk.z = (u32)f2bf(v1[0]) | ((u32)f2bf(v1[1]) << 16);
        pk.w = (u32)f2bf(v1[2]) | ((u32)f2bf(v1[3]) << 16);
      } else {
        pk = *(const uint4*)&((const u16*)src)[g];
      }
      *(uint4*)&lA[row * 32 + c0] = pk;
    }
    stage128x32(WaT + k0, 256, lB, wave, lane);
    stage128x32(WaT + (size_t)128 * 256 + k0, 256, lB + 4096, wave, lane);
    __syncthreads();
    bf8 af[4], bfr[4];
#pragma unroll
    for (int mi = 0; mi < 4; ++mi) af[mi] = *(const bf8*)&lA[(mi * 16 + col) * 32 + quad * 8];
#pragma unroll
    for (int nj = 0; nj < 4; ++nj) bfr[nj] = *(const bf8*)&lB[(wave * 64 + nj * 16 + col) * 32 + quad * 8];
#pragma unroll
    for (int mi = 0; mi < 4; ++mi)
#pragma unroll
      for (int nj = 0; nj < 4; ++nj)
        acc[mi][nj] = __builtin_amdgcn_mfma_f32_16x16x32_bf16(af[mi], bfr[nj], acc[mi][nj], 0, 0, 0);
  }
#pragma unroll
  for (int mi = 0; mi < 4; ++mi)
#pragma unroll
    for (int nj = 0; nj < 4; ++nj) {
      int o = wave * 64 + nj * 16 + col;
      float bav = ldf(ba, o, isf32);
      int rl = mi * 16 + quad * 4;
#pragma unroll
      for (int r = 0; r < 4; ++r)
        Z[(rl + r) * 264 + o] = f2bf(fmaxf(acc[mi][nj][r] + bav, 0.f));
    }
  __syncthreads();

  // phase 2: h0 = tanh(Z @ Wb + bb); A-frags from Z (stride 264)
  f4 acc2[4][2] = {};
  for (int kk = 0; kk < 8; ++kk) {
    int k0 = kk * 32;
    if (kk) __syncthreads();
    stage128x32(WbT + k0, 256, lB, wave, lane);
    __syncthreads();
    bf8 az[4], bw[2];
#pragma unroll
    for (int mi = 0; mi < 4; ++mi) az[mi] = *(const bf8*)&Z[(mi * 16 + col) * 264 + k0 + quad * 8];
#pragma unroll
    for (int nj = 0; nj < 2; ++nj) bw[nj] = *(const bf8*)&lB[(wave * 32 + nj * 16 + col) * 32 + quad * 8];
#pragma unroll
    for (int mi = 0; mi < 4; ++mi)
#pragma unroll
      for (int nj = 0; nj < 2; ++nj)
        acc2[mi][nj] = __builtin_amdgcn_mfma_f32_16x16x32_bf16(az[mi], bw[nj], acc2[mi][nj], 0, 0, 0);
  }
  __syncthreads();   // all waves done with lB before hN overlay

  // epilogue: tanh(+bb) -> global hT (transposed) AND hN[r][d] staging for hW1
#pragma unroll
  for (int mi = 0; mi < 4; ++mi)
#pragma unroll
    for (int nj = 0; nj < 2; ++nj) {
      int d = wave * 32 + nj * 16 + col;
      float bbv = ldf(bb, d, isf32);
      int rl = mi * 16 + quad * 4;
      int rabs = r0 + rl;
      int n = rabs & 2047;
      u16 p[4];
#pragma unroll
      for (int r = 0; r < 4; ++r) {
        p[r] = f2bf(tanhf(acc2[mi][nj][r] + bbv));
        hN[(rl + r) * 136 + d] = p[r];
      }
      u64 pk = (u64)p[0] | ((u64)p[1] << 16) | ((u64)p[2] << 32) | ((u64)p[3] << 48);
      *(u64*)&hT[(size_t)(b * 128 + d) * 2048 + n] = pk;
    }
  __syncthreads();

  // hW1: out[j][r] = sum_d W1T[j][d] * hN[r][d]; wave covers r in [wave*16, wave*16+16)
  f4 acc3[4] = {};
#pragma unroll
  for (int ks = 0; ks < 4; ++ks) {
    bf8 aw[4], bg;
#pragma unroll
    for (int mi = 0; mi < 4; ++mi)
      aw[mi] = *(const bf8*)&W1T[(size_t)(mi * 16 + col) * 128 + ks * 32 + quad * 8];
    bg = *(const bf8*)&hN[(wave * 16 + col) * 136 + ks * 32 + quad * 8];
#pragma unroll
    for (int mi = 0; mi < 4; ++mi)
      acc3[mi] = __builtin_amdgcn_mfma_f32_16x16x32_bf16(aw[mi], bg, acc3[mi], 0, 0, 0);
  }
#pragma unroll
  for (int mi = 0; mi < 4; ++mi) {
    int rloc = wave * 16 + col;
    int ng = (r0 & 2047) + rloc;
#pragma unroll
    for (int r = 0; r < 4; ++r) {
      int j = mi * 16 + quad * 4 + r;
      hW[(size_t)(b * 64 + j) * 2048 + ng] = f2bf(acc3[mi][r]);
    }
  }
}

// ---------------- fused diffusion step (R0 structure + fused final output) ----
// Big GEMM: G[m=(b,j)][n2] = sum_n hWT[(b*64+j)][n] * adjb[n2][n]  (64x128 tile, K=2048)
// Update: nh = hin + DT*tanh(G)  (eps step: *= clip(eps,0,0.1)); write updated half +
// copy untouched half to hout. If WnT: stage hnew into gN[n][d] and produce next
// hWout[(b*64+j')][n] = sum_d WnT[j'][d] * gN[n][d]  (in-LDS pass-2).
// If fout != nullptr (final step): skip all hout writes; stage the full new h
// tile into gN[n][d] and write fout[b][n][d] directly (coalesced 512B rows).
__global__ __launch_bounds__(256, 2) void fused_step2(const u16* __restrict__ hin,
                                                      const u16* __restrict__ hWT,
                                                      const u16* __restrict__ adjb,
                                                      const u16* __restrict__ WnT,
                                                      const void* __restrict__ eps,
                                                      u16* __restrict__ hout,
                                                      u16* __restrict__ hWout,
                                                      void* __restrict__ fout,
                                                      int half, const u32* __restrict__ flag) {
  __shared__ __align__(16) u16 smem[24576];   // 48 KB
  u16* lA = smem;               // 4 panels x [64][32]
  u16* lB = smem + 8192;        // 4 panels x [128][32]
  u16* gN = smem;               // [128][136] = 17408 u16, overlays lA/lB post K-loop
  u32 isf32 = flag[0];
  int tid = threadIdx.x, lane = tid & 63, wave = tid >> 6;
  int col = lane & 15, quad = lane >> 4;
  int b = blockIdx.y;
  int n0 = blockIdx.x * 128;

  const u16* Arow = hWT + (size_t)(b * 64) * 2048;
  const u16* Brow = adjb + (size_t)n0 * 2048;

  f4 acc[4][2] = {};
  for (int kk = 0; kk < 16; ++kk) {
    int k0 = kk * 128;
#pragma unroll
    for (int p = 0; p < 4; ++p) {
      stage64x32(Arow + k0 + p * 32, 2048, lA + p * 2048, wave, lane);
      stage128x32(Brow + k0 + p * 32, 2048, lB + p * 4096, wave, lane);
    }
    __syncthreads();
#pragma unroll
    for (int p = 0; p < 4; ++p) {
      bf8 af[4], bfr[2];
#pragma unroll
      for (int mi = 0; mi < 4; ++mi) af[mi] = *(const bf8*)&lA[p * 2048 + (mi * 16 + col) * 32 + quad * 8];
#pragma unroll
      for (int nj = 0; nj < 2; ++nj) bfr[nj] = *(const bf8*)&lB[p * 4096 + (wave * 32 + nj * 16 + col) * 32 + quad * 8];
#pragma unroll
      for (int mi = 0; mi < 4; ++mi)
#pragma unroll
        for (int nj = 0; nj < 2; ++nj)
          acc[mi][nj] = __builtin_amdgcn_mfma_f32_16x16x32_bf16(af[mi], bfr[nj], acc[mi][nj], 0, 0, 0);
    }
    __syncthreads();
  }

  bool has_eps = (eps != nullptr);
  bool mk_hw = (WnT != nullptr);
  bool fin = (fout != nullptr);
  bool stage_gN = mk_hw || fin;
  int dBase = half * 64;
  // update + write updated half (skipped when fin); stage nh into gN[n][dBase+j]
#pragma unroll
  for (int mi = 0; mi < 4; ++mi)
#pragma unroll
    for (int nj = 0; nj < 2; ++nj) {
      int j0 = mi * 16 + quad * 4;
      int nl = wave * 32 + nj * 16 + col;
      int n = n0 + nl;
      float ev[4];
      if (has_eps) {
        size_t eoff = ((size_t)b * 2048 + n) * 64 + j0;
        if (isf32) {
          f4 e = *(const f4*)&((const float*)eps)[eoff];
          ev[0] = e[0]; ev[1] = e[1]; ev[2] = e[2]; ev[3] = e[3];
        } else {
          u64 e = *(const u64*)&((const u16*)eps)[eoff];
          ev[0] = bf2f((u16)e); ev[1] = bf2f((u16)(e >> 16));
          ev[2] = bf2f((u16)(e >> 32)); ev[3] = bf2f((u16)(e >> 48));
        }
      }
      u16 pv[4];
#pragma unroll
      for (int r = 0; r < 4; ++r) {
        int j = j0 + r;
        size_t idx = (size_t)(b * 128 + dBase + j) * 2048 + n;
        float hold = bf2f(hin[idx]);
        float nh = hold + 0.01f * tanhf(acc[mi][nj][r]);
        if (has_eps) {
          float e = fminf(fmaxf(ev[r], 0.f), 0.1f);
          nh = e * nh;
        }
        pv[r] = f2bf(nh);
        if (!fin) hout[idx] = pv[r];
      }
      if (stage_gN) {
        u64 pk = (u64)pv[0] | ((u64)pv[1] << 16) | ((u64)pv[2] << 32) | ((u64)pv[3] << 48);
        *(u64*)&gN[nl * 136 + dBase + j0] = pk;
      }
    }

  // copy untouched half to hout (skipped when fin); scatter into gN[n][oh+row]
  {
    int oh = (1 - half) * 64;
    const u16* src = hin + (size_t)(b * 128 + oh) * 2048 + n0;
    u16* dst = hout + (size_t)(b * 128 + oh) * 2048 + n0;
#pragma unroll
    for (int i = 0; i < 4; ++i) {
      int idx = i * 256 + tid;
      int rr = idx >> 4;
      int cc = (idx & 15) * 8;
      uint4 v = *(const uint4*)&src[(size_t)rr * 2048 + cc];
      if (!fin) *(uint4*)&dst[(size_t)rr * 2048 + cc] = v;
      if (stage_gN) {
        u16 t[8];
        *(uint4*)t = v;
#pragma unroll
        for (int q = 0; q < 8; ++q) gN[(cc + q) * 136 + oh + rr] = t[q];
      }
    }
  }

  if (mk_hw) {
    __syncthreads();
    // next hW: out[j'][n] = sum_d WnT[j'][d] * gN[n][d]
    f4 acc2[4][2] = {};
#pragma unroll
    for (int ks = 0; ks < 4; ++ks) {
      bf8 aw[4], bg[2];
#pragma unroll
      for (int mi = 0; mi < 4; ++mi)
        aw[mi] = *(const bf8*)&WnT[(size_t)(mi * 16 + col) * 128 + ks * 32 + quad * 8];
#pragma unroll
      for (int nj = 0; nj < 2; ++nj)
        bg[nj] = *(const bf8*)&gN[(wave * 32 + nj * 16 + col) * 136 + ks * 32 + quad * 8];
#pragma unroll
      for (int mi = 0; mi < 4; ++mi)
#pragma unroll
        for (int nj = 0; nj < 2; ++nj)
          acc2[mi][nj] = __builtin_amdgcn_mfma_f32_16x16x32_bf16(aw[mi], bg[nj], acc2[mi][nj], 0, 0, 0);
    }
#pragma unroll
    for (int mi = 0; mi < 4; ++mi)
#pragma unroll
      for (int nj = 0; nj < 2; ++nj) {
        int jp0 = mi * 16 + quad * 4;
        int n = n0 + wave * 32 + nj * 16 + col;
#pragma unroll
        for (int r = 0; r < 4; ++r)
          hWout[(size_t)(b * 64 + jp0 + r) * 2048 + n] = f2bf(acc2[mi][nj][r]);
      }
  }

  if (fin) {
    __syncthreads();
    // final output: out[b][n0+n][d] from gN[n][d]; lanes 0..31 cover d (f32x4)
    // -> 512B contiguous per n-row, 8 rows/pass, 16 passes.
    int d4 = (tid & 31) * 4;
    int nb = tid >> 5;                  // 0..7
#pragma unroll
    for (int p = 0; p < 16; ++p) {
      int n = p * 8 + nb;
      u64 v = *(const u64*)&gN[n * 136 + d4];
      size_t o = ((size_t)b * 2048 + n0 + n) * 128 + d4;
      if (isf32) {
        f4 w;
        w[0] = bf2f((u16)v); w[1] = bf2f((u16)(v >> 16));
        w[2] = bf2f((u16)(v >> 32)); w[3] = bf2f((u16)(v >> 48));
        *(f4*)&((float*)fout)[o] = w;
      } else {
        *(u64*)&((u16*)fout)[o] = v;
      }
    }
  }
}

extern "C" void kernel_launch(void* const* d_in, const int* in_sizes, int n_in,
                              void* d_out, int out_size, void* d_ws, size_t ws_size,
                              hipStream_t stream) {
  const void* x   = d_in[0];
  const void* hz  = d_in[1];
  const void* adj = d_in[2];
  const void* W1  = d_in[3];
  const void* W2  = d_in[4];
  const void* Wa  = d_in[5];
  const void* ba  = d_in[6];
  const void* Wb  = d_in[7];
  const void* bb  = d_in[8];
  const void* eps = d_in[9];

  // workspace layout (44.3 MB):
  //   hA   @  0M   16.78 MB  transposed h ping buffer (bf16 [4096][2048])
  //   adjb @ 17M    8.39 MB  adj bf16 [2048][2048]
  //   hWa  @ 26M    8.39 MB  hW ping (bf16 [2048][2048])
  //   hWb  @ 35M    8.39 MB  hW pong
  //   weights @ 44M (229 KB), flag after
  // hB (pong h) = d_out scratch (bf16 [4096][2048] = 16.8 MB fits both dtypes);
  // step 4 reads hA and writes the FINAL result directly to d_out (fused
  // untranspose) — no overlap since step 4's hin is hA.
  char* ws = (char*)d_ws;
  u16* hA   = (u16*)(ws);
  u16* adjb = (u16*)(ws + (17ull << 20));
  u16* hWa  = (u16*)(ws + (26ull << 20));
  u16* hWb  = (u16*)(ws + (35ull << 20));
  u16* WaT  = (u16*)(ws + (44ull << 20));
  u16* WbT  = WaT + 256 * 256;
  u16* W1T  = WbT + 128 * 256;
  u16* W2T  = W1T + 64 * 128;
  u32* flag = (u32*)(W2T + 64 * 128);
  u16* hB   = (u16*)d_out;

  detect_dtype<<<dim3(1), dim3(256), 0, stream>>>((const u16*)x, flag);
  prep_weights<<<dim3(448), dim3(256), 0, stream>>>(Wa, Wb, W1, W2, WaT, WbT, W1T, W2T, flag);
  cvt_bf16<<<dim3(4096), dim3(256), 0, stream>>>(adj, adjb, 0, 4194304, flag);
  // mlp writes h0 -> hB (=d_out scratch) so the ping-pong ends on hA before step 4
  mlp_fused<<<dim3(1024), dim3(256), 0, stream>>>(x, hz, WaT, ba, WbT, bb, W1T, hB, hWa, flag);
  // step 1 (half=0, consumes hWa=h0@W1h, produces hWb=h1@W2h): hB -> hA
  fused_step2<<<dim3(16, 32), dim3(256), 0, stream>>>(hB, hWa, adjb, W2T, nullptr, hA, hWb, nullptr, 0, flag);
  // step 2 (half=1, eps; consumes hWb, produces hWa=h2@W1h): hA -> hB
  fused_step2<<<dim3(16, 32), dim3(256), 0, stream>>>(hA, hWb, adjb, W1T, eps, hB, hWa, nullptr, 1, flag);
  // step 3 (half=0; consumes hWa, produces hWb=h3@W2h): hB -> hA
  fused_step2<<<dim3(16, 32), dim3(256), 0, stream>>>(hB, hWa, adjb, W2T, nullptr, hA, hWb, nullptr, 0, flag);
  // step 4 (half=1, eps; consumes hWb): hA -> d_out directly (fused untranspose)
  fused_step2<<<dim3(16, 32), dim3(256), 0, stream>>>(hA, hWb, adjb, nullptr, eps, hB, nullptr, d_out, 1, flag);
}